// Round 1
// baseline (1889.167 us; speedup 1.0000x reference)
//
#include <hip/hip_runtime.h>
#include <hip/hip_bf16.h>
#include <math.h>

// ---------------- constants ----------------
constexpr int B_TOK = 16384;
constexpr int DIM   = 1024;
constexpr int NEXP  = 8;
constexpr int FFN   = 2048;
constexpr int NSLOT = B_TOK * 2;     // top-2 -> exactly 2 slots per token
constexpr int FCHUNK = 1024;         // FFN processed in two 1024-wide chunks

typedef __attribute__((ext_vector_type(8))) short bf16x8;
typedef __attribute__((ext_vector_type(4))) float f32x4;

// fp32 -> bf16 round-to-nearest-even (values are finite/normal here)
static __device__ __forceinline__ unsigned short f2bf(float f) {
    unsigned int u = __float_as_uint(f);
    u += 0x7fffu + ((u >> 16) & 1u);
    return (unsigned short)(u >> 16);
}

static __device__ __forceinline__ void gl_lds16(const unsigned short* g, unsigned short* s) {
    // async global->LDS, 16B per lane; LDS dest = wave-uniform base + lane*16
    __builtin_amdgcn_global_load_lds(
        (const __attribute__((address_space(1))) unsigned int*)g,
        (__attribute__((address_space(3))) unsigned int*)s, 16, 0, 0);
}

// ---------------- gating: logits, top-2, softmax, counts, x->bf16 ----------------
__global__ __launch_bounds__(256) void k_gate(const float* __restrict__ x,
        const float* __restrict__ gw, unsigned short* __restrict__ xb,
        int* __restrict__ e0a, int* __restrict__ e1a,
        float* __restrict__ w0a, float* __restrict__ w1a,
        int* __restrict__ counts) {
    __shared__ float gwl[DIM * NEXP];
    int tid = threadIdx.x;
    for (int i = tid; i < DIM * NEXP / 4; i += 256)
        ((float4*)gwl)[i] = ((const float4*)gw)[i];
    __syncthreads();

    int wv = tid >> 6, l = tid & 63;
    int t = blockIdx.x * 4 + wv;
    const float* xr = x + (size_t)t * DIM;
    unsigned short* xbr = xb + (size_t)t * DIM;

    float acc[NEXP];
#pragma unroll
    for (int e = 0; e < NEXP; e++) acc[e] = 0.f;

#pragma unroll
    for (int it = 0; it < 4; it++) {
        int k0 = it * 256 + l * 4;
        float4 xv = *(const float4*)(xr + k0);
        *(ushort4*)(xbr + k0) = make_ushort4(f2bf(xv.x), f2bf(xv.y), f2bf(xv.z), f2bf(xv.w));
        float xs[4] = {xv.x, xv.y, xv.z, xv.w};
#pragma unroll
        for (int j = 0; j < 4; j++) {
            const float* g = gwl + (size_t)(k0 + j) * NEXP;
#pragma unroll
            for (int e = 0; e < NEXP; e++) acc[e] += xs[j] * g[e];
        }
    }
#pragma unroll
    for (int e = 0; e < NEXP; e++) {
        float v = acc[e];
#pragma unroll
        for (int off = 32; off; off >>= 1) v += __shfl_xor(v, off);
        acc[e] = v;
    }
    if (l == 0) {
        int b0 = -1, b1 = -1;
        float v0 = -INFINITY, v1 = -INFINITY;
#pragma unroll
        for (int e = 0; e < NEXP; e++) {
            float v = acc[e];
            if (v > v0)      { v1 = v0; b1 = b0; v0 = v; b0 = e; }
            else if (v > v1) { v1 = v;  b1 = e; }
        }
        float ex = expf(v1 - v0);
        float w0 = 1.f / (1.f + ex);
        e0a[t] = b0; e1a[t] = b1; w0a[t] = w0; w1a[t] = ex / (1.f + ex);
        atomicAdd(&counts[b0], 1);
        atomicAdd(&counts[b1], 1);
    }
}

__global__ void k_offsets(const int* __restrict__ counts, int* __restrict__ offs,
                          int* __restrict__ cursor) {
    int s = 0;
    for (int e = 0; e < NEXP; e++) { offs[e] = s; cursor[e] = s; s += counts[e]; }
    offs[NEXP] = s;
}

__global__ __launch_bounds__(256) void k_scatter(const int* __restrict__ e0a,
        const int* __restrict__ e1a, const float* __restrict__ w0a,
        const float* __restrict__ w1a, int* __restrict__ cursor,
        int* __restrict__ slot_tok, float* __restrict__ slot_w) {
    int t = blockIdx.x * 256 + threadIdx.x;
    int p0 = atomicAdd(&cursor[e0a[t]], 1);
    slot_tok[p0] = t; slot_w[p0] = w0a[t];
    int p1 = atomicAdd(&cursor[e1a[t]], 1);
    slot_tok[p1] = t; slot_w[p1] = w1a[t];
}

// ---------------- transpose + cast: src[z][R][C] f32 -> dst[z][C][R] bf16 ----------------
__global__ __launch_bounds__(256) void k_transpose_cast(const float* __restrict__ src,
        unsigned short* __restrict__ dst, int R, int C) {
    __shared__ float tile[32][33];
    int z = blockIdx.z;
    const float* s = src + (size_t)z * R * C;
    unsigned short* d = dst + (size_t)z * R * C;
    int c0 = blockIdx.x * 32, r0 = blockIdx.y * 32;
    int tx = threadIdx.x & 31, ty = threadIdx.x >> 5;   // ty: 0..7
#pragma unroll
    for (int i = 0; i < 4; i++)
        tile[ty + i * 8][tx] = s[(size_t)(r0 + ty + i * 8) * C + c0 + tx];
    __syncthreads();
#pragma unroll
    for (int i = 0; i < 4; i++)
        d[(size_t)(c0 + ty + i * 8) * R + r0 + tx] = f2bf(tile[tx][ty + i * 8]);
}

// ---------------- grouped GEMM (m97 structure: 128x128 tile, BK=64, 4 waves) ----------------
// MODE 0: Hout[slot][colg] = bf16(gelu(acc + b1))      (A rows gathered if GATHER)
// MODE 1: atomicAdd(Out[tok][colg], w * (acc + b2))
template<int MODE, bool GATHER>
__global__ __launch_bounds__(256) void k_gemm(
    const unsigned short* __restrict__ A, int Astride,
    const unsigned short* __restrict__ Bt, size_t BtEStride, int BtRowStride,
    const float* __restrict__ bias, int biasEStride,
    const int* __restrict__ offs,
    const int* __restrict__ slot_tok, const float* __restrict__ slot_w,
    unsigned short* __restrict__ Hout, int HoutStride,
    float* __restrict__ Out,
    int K, int N)
{
    int e   = blockIdx.z;
    int off = offs ? offs[e] : 0;
    int cnt = offs ? (offs[e + 1] - off) : B_TOK;
    int m0  = blockIdx.x * 128;
    if (m0 >= cnt) return;
    int n0  = blockIdx.y * 128;
    const unsigned short* Bte = Bt + (size_t)e * BtEStride;

    __shared__ unsigned short Al[128 * 64];
    __shared__ unsigned short Bl[128 * 64];

    int tid = threadIdx.x;
    int w = tid >> 6, l = tid & 63;
    int larow = l >> 3;        // row within 8-row chunk
    int lk    = (l & 7) * 8;   // k element offset (16B granule)

    // per-thread source rows for the 4 staging chunks (fixed across K-steps)
    size_t asrc[4], bsrc[4];
#pragma unroll
    for (int i = 0; i < 4; i++) {
        int c = i * 4 + w;
        int r = c * 8 + larow;            // 0..127 within tile
        int gs = m0 + r;
        int srcrow;
        if (GATHER) {
            int slot = off + gs; if (slot > NSLOT - 1) slot = NSLOT - 1;
            srcrow = slot_tok[slot];
        } else {
            int slot = off + gs;
            int maxr = offs ? (NSLOT - 1) : (B_TOK - 1);
            if (slot > maxr) slot = maxr;
            srcrow = slot;
        }
        asrc[i] = (size_t)srcrow * Astride + lk;
        bsrc[i] = (size_t)(n0 + r) * BtRowStride + lk;
    }

    f32x4 acc[4][4];
#pragma unroll
    for (int mi = 0; mi < 4; mi++)
#pragma unroll
        for (int ni = 0; ni < 4; ni++) acc[mi][ni] = (f32x4){0.f, 0.f, 0.f, 0.f};

    int wr = w >> 1, wc = w & 1;
    int arow_f = wr * 64 + (l & 15);
    int brow_f = wc * 64 + (l & 15);
    int g = l >> 4;

    for (int k0 = 0; k0 < K; k0 += 64) {
#pragma unroll
        for (int i = 0; i < 4; i++) {
            int c = i * 4 + w;
            gl_lds16(A + asrc[i] + k0,   Al + (size_t)c * 512);
            gl_lds16(Bte + bsrc[i] + k0, Bl + (size_t)c * 512);
        }
        __syncthreads();
#pragma unroll
        for (int ks = 0; ks < 2; ks++) {
            bf16x8 af[4], bfr[4];
#pragma unroll
            for (int mi = 0; mi < 4; mi++)
                af[mi] = *(const bf16x8*)(Al + (size_t)(arow_f + mi * 16) * 64 + ks * 32 + g * 8);
#pragma unroll
            for (int ni = 0; ni < 4; ni++)
                bfr[ni] = *(const bf16x8*)(Bl + (size_t)(brow_f + ni * 16) * 64 + ks * 32 + g * 8);
#pragma unroll
            for (int mi = 0; mi < 4; mi++)
#pragma unroll
                for (int ni = 0; ni < 4; ni++)
                    acc[mi][ni] = __builtin_amdgcn_mfma_f32_16x16x32_bf16(
                        af[mi], bfr[ni], acc[mi][ni], 0, 0, 0);
        }
        __syncthreads();
    }

    // epilogue — C/D layout (verified): col = lane&15, row = (lane>>4)*4 + reg
    int rg = l >> 4, cl = l & 15;
    float bvs[4];
#pragma unroll
    for (int ni = 0; ni < 4; ni++) {
        int colg = n0 + wc * 64 + ni * 16 + cl;
        bvs[ni] = bias ? bias[(size_t)e * biasEStride + colg] : 0.f;
    }
#pragma unroll
    for (int mi = 0; mi < 4; mi++) {
#pragma unroll
        for (int j = 0; j < 4; j++) {
            int rl = wr * 64 + mi * 16 + rg * 4 + j;
            if (m0 + rl >= cnt) continue;
            int slot = off + m0 + rl;
            if (MODE == 0) {
#pragma unroll
                for (int ni = 0; ni < 4; ni++) {
                    int colg = n0 + wc * 64 + ni * 16 + cl;
                    float hv = acc[mi][ni][j] + bvs[ni];
                    float ge = 0.5f * hv * (1.f + erff(hv * 0.70710678118654752f));
                    Hout[(size_t)slot * HoutStride + colg] = f2bf(ge);
                }
            } else {
                int tok; float wgt;
                if (slot_w) { tok = slot_tok[slot]; wgt = slot_w[slot]; }
                else        { tok = slot;           wgt = 1.f; }
#pragma unroll
                for (int ni = 0; ni < 4; ni++) {
                    int colg = n0 + wc * 64 + ni * 16 + cl;
                    atomicAdd(&Out[(size_t)tok * DIM + colg], wgt * (acc[mi][ni][j] + bvs[ni]));
                }
            }
        }
    }
}

// ---------------- LayerNorm(acc + x) in-place on out ----------------
__global__ __launch_bounds__(256) void k_ln(float* __restrict__ out,
        const float* __restrict__ x, const float* __restrict__ gamma,
        const float* __restrict__ beta) {
    int wv = threadIdx.x >> 6, l = threadIdx.x & 63;
    int t = blockIdx.x * 4 + wv;
    float* orow = out + (size_t)t * DIM;
    const float* xrow = x + (size_t)t * DIM;
    float z[16];
    float s = 0.f;
#pragma unroll
    for (int it = 0; it < 4; it++) {
        int k0 = it * 256 + l * 4;
        float4 a = *(const float4*)(orow + k0);
        float4 b = *(const float4*)(xrow + k0);
        z[it * 4 + 0] = a.x + b.x; z[it * 4 + 1] = a.y + b.y;
        z[it * 4 + 2] = a.z + b.z; z[it * 4 + 3] = a.w + b.w;
        s += z[it * 4 + 0] + z[it * 4 + 1] + z[it * 4 + 2] + z[it * 4 + 3];
    }
#pragma unroll
    for (int off = 32; off; off >>= 1) s += __shfl_xor(s, off);
    float mu = s * (1.f / 1024.f);
    float vs = 0.f;
#pragma unroll
    for (int i = 0; i < 16; i++) { float d = z[i] - mu; vs += d * d; }
#pragma unroll
    for (int off = 32; off; off >>= 1) vs += __shfl_xor(vs, off);
    float rs = 1.f / sqrtf(vs * (1.f / 1024.f) + 1e-5f);
#pragma unroll
    for (int it = 0; it < 4; it++) {
        int k0 = it * 256 + l * 4;
        float4 gm = *(const float4*)(gamma + k0);
        float4 be = *(const float4*)(beta + k0);
        float4 o;
        o.x = (z[it * 4 + 0] - mu) * rs * gm.x + be.x;
        o.y = (z[it * 4 + 1] - mu) * rs * gm.y + be.y;
        o.z = (z[it * 4 + 2] - mu) * rs * gm.z + be.z;
        o.w = (z[it * 4 + 3] - mu) * rs * gm.w + be.w;
        *(float4*)(orow + k0) = o;
    }
}

// ---------------- launch ----------------
extern "C" void kernel_launch(void* const* d_in, const int* in_sizes, int n_in,
                              void* d_out, int out_size, void* d_ws, size_t ws_size,
                              hipStream_t stream) {
    (void)in_sizes; (void)n_in; (void)ws_size;
    const float* x      = (const float*)d_in[0];
    const float* gate_w = (const float*)d_in[1];
    const float* W1     = (const float*)d_in[2];
    const float* b1     = (const float*)d_in[3];
    const float* W2     = (const float*)d_in[4];
    const float* b2     = (const float*)d_in[5];
    const float* sW1    = (const float*)d_in[6];
    const float* sb1    = (const float*)d_in[7];
    const float* sW2    = (const float*)d_in[8];
    const float* sb2    = (const float*)d_in[9];
    const float* gamma  = (const float*)d_in[10];
    const float* beta   = (const float*)d_in[11];
    float* out = (float*)d_out;

    // workspace carve (total ~177 MB)
    char* p = (char*)d_ws;
    auto carve = [&](size_t n) { char* r = p; p += (n + 255) & ~(size_t)255; return r; };
    unsigned short* xb    = (unsigned short*)carve((size_t)B_TOK * DIM * 2);
    unsigned short* W1t   = (unsigned short*)carve((size_t)NEXP * FFN * DIM * 2); // [e][f][d]
    unsigned short* W2t   = (unsigned short*)carve((size_t)NEXP * DIM * FFN * 2); // [e][d][f]
    unsigned short* sW1t  = (unsigned short*)carve((size_t)FFN * DIM * 2);        // [f][d]
    unsigned short* sW2t  = (unsigned short*)carve((size_t)DIM * FFN * 2);        // [d][f]
    unsigned short* hbuf  = (unsigned short*)carve((size_t)NSLOT * FCHUNK * 2);   // 67 MB
    int*   e0a      = (int*)carve((size_t)B_TOK * 4);
    int*   e1a      = (int*)carve((size_t)B_TOK * 4);
    float* w0a      = (float*)carve((size_t)B_TOK * 4);
    float* w1a      = (float*)carve((size_t)B_TOK * 4);
    int*   slot_tok = (int*)carve((size_t)NSLOT * 4);
    float* slot_w   = (float*)carve((size_t)NSLOT * 4);
    int*   counts   = (int*)carve(64);
    int*   offs     = (int*)carve(64);
    int*   cursor   = (int*)carve(64);

    hipMemsetAsync(counts, 0, 64, stream);
    hipMemsetAsync(d_out, 0, (size_t)out_size * 4, stream);

    k_gate<<<B_TOK / 4, 256, 0, stream>>>(x, gate_w, xb, e0a, e1a, w0a, w1a, counts);
    k_offsets<<<1, 1, 0, stream>>>(counts, offs, cursor);
    k_scatter<<<B_TOK / 256, 256, 0, stream>>>(e0a, e1a, w0a, w1a, cursor, slot_tok, slot_w);

    k_transpose_cast<<<dim3(FFN / 32, DIM / 32, NEXP), 256, 0, stream>>>(W1, W1t, DIM, FFN);
    k_transpose_cast<<<dim3(DIM / 32, FFN / 32, NEXP), 256, 0, stream>>>(W2, W2t, FFN, DIM);
    k_transpose_cast<<<dim3(FFN / 32, DIM / 32, 1), 256, 0, stream>>>(sW1, sW1t, DIM, FFN);
    k_transpose_cast<<<dim3(DIM / 32, FFN / 32, 1), 256, 0, stream>>>(sW2, sW2t, FFN, DIM);

    // experts: two FFN chunks of 1024, h staged in hbuf between the two GEMMs
    for (int c = 0; c < 2; c++) {
        size_t f0 = (size_t)c * FCHUNK;
        k_gemm<0, true><<<dim3(128, 8, NEXP), 256, 0, stream>>>(
            xb, DIM,
            W1t + f0 * DIM, (size_t)FFN * DIM, DIM,
            b1 + f0, FFN,
            offs, slot_tok, nullptr,
            hbuf, FCHUNK, nullptr, DIM, FCHUNK);
        k_gemm<1, false><<<dim3(128, 8, NEXP), 256, 0, stream>>>(
            hbuf, FCHUNK,
            W2t + f0, (size_t)DIM * FFN, FFN,
            (c == 0) ? b2 : nullptr, DIM,
            offs, slot_tok, slot_w,
            nullptr, 0, out, FCHUNK, DIM);
    }
    // shared expert: same machinery, identity routing, weight 1
    for (int c = 0; c < 2; c++) {
        size_t f0 = (size_t)c * FCHUNK;
        k_gemm<0, false><<<dim3(128, 8, 1), 256, 0, stream>>>(
            xb, DIM,
            sW1t + f0 * DIM, 0, DIM,
            sb1 + f0, 0,
            nullptr, nullptr, nullptr,
            hbuf, FCHUNK, nullptr, DIM, FCHUNK);
        k_gemm<1, false><<<dim3(128, 8, 1), 256, 0, stream>>>(
            hbuf, FCHUNK,
            sW2t + f0, 0, FFN,
            (c == 0) ? sb2 : nullptr, 0,
            nullptr, nullptr, nullptr,
            nullptr, 0, out, FCHUNK, DIM);
    }

    k_ln<<<B_TOK / 4, 256, 0, stream>>>(out, x, gamma, beta);
}

// Round 2
// 1465.997 us; speedup vs baseline: 1.2887x; 1.2887x over previous
//
#include <hip/hip_runtime.h>
#include <hip/hip_bf16.h>
#include <math.h>

// ---------------- constants ----------------
constexpr int B_TOK = 16384;
constexpr int DIM   = 1024;
constexpr int NEXP  = 8;
constexpr int FFN   = 2048;
constexpr int NSLOT = B_TOK * 2;     // top-2 -> exactly 2 slots per token
constexpr int FCHUNK = 1024;         // FFN processed in two 1024-wide chunks
constexpr int CNT_BLOCKS = B_TOK / 256;  // 64 blocks for count/scatter

typedef __attribute__((ext_vector_type(8))) short bf16x8;
typedef __attribute__((ext_vector_type(4))) float f32x4;

// fp32 -> bf16 round-to-nearest-even (values are finite/normal here)
static __device__ __forceinline__ unsigned short f2bf(float f) {
    unsigned int u = __float_as_uint(f);
    u += 0x7fffu + ((u >> 16) & 1u);
    return (unsigned short)(u >> 16);
}

static __device__ __forceinline__ void gl_lds16(const unsigned short* g, unsigned short* s) {
    // async global->LDS, 16B per lane; LDS dest = wave-uniform base + lane*16
    __builtin_amdgcn_global_load_lds(
        (const __attribute__((address_space(1))) unsigned int*)g,
        (__attribute__((address_space(3))) unsigned int*)s, 16, 0, 0);
}

// ---------------- gating: logits + top-2 + softmax + x->bf16 (no LDS, no atomics) ----------------
__global__ __launch_bounds__(256) void k_gate(const float* __restrict__ x,
        const float* __restrict__ gw, unsigned short* __restrict__ xb,
        int* __restrict__ e0a, int* __restrict__ e1a,
        float* __restrict__ w0a, float* __restrict__ w1a) {
    int tid = threadIdx.x;
    int wv = tid >> 6, l = tid & 63;
    int t = blockIdx.x * 4 + wv;
    const float* xr = x + (size_t)t * DIM;
    unsigned short* xbr = xb + (size_t)t * DIM;
    const float4* gwv = (const float4*)gw;   // gw[k][e], float4 idx = k*2, k*2+1

    float acc[NEXP];
#pragma unroll
    for (int e = 0; e < NEXP; e++) acc[e] = 0.f;

#pragma unroll
    for (int it = 0; it < 4; it++) {
        int k0 = it * 256 + l * 4;
        float4 xv = *(const float4*)(xr + k0);
        *(ushort4*)(xbr + k0) = make_ushort4(f2bf(xv.x), f2bf(xv.y), f2bf(xv.z), f2bf(xv.w));
        float xs[4] = {xv.x, xv.y, xv.z, xv.w};
#pragma unroll
        for (int j = 0; j < 3; j++) { // j = 0..3 unrolled below (avoid runtime idx)
        }
#pragma unroll
        for (int j = 0; j < 4; j++) {
            int k = k0 + j;
            float4 g0 = gwv[k * 2];
            float4 g1 = gwv[k * 2 + 1];
            float xs1 = xs[j];
            acc[0] += xs1 * g0.x; acc[1] += xs1 * g0.y;
            acc[2] += xs1 * g0.z; acc[3] += xs1 * g0.w;
            acc[4] += xs1 * g1.x; acc[5] += xs1 * g1.y;
            acc[6] += xs1 * g1.z; acc[7] += xs1 * g1.w;
        }
    }
#pragma unroll
    for (int e = 0; e < NEXP; e++) {
        float v = acc[e];
#pragma unroll
        for (int off = 32; off; off >>= 1) v += __shfl_xor(v, off);
        acc[e] = v;
    }
    if (l == 0) {
        int b0 = -1, b1 = -1;
        float v0 = -INFINITY, v1 = -INFINITY;
#pragma unroll
        for (int e = 0; e < NEXP; e++) {
            float v = acc[e];
            if (v > v0)      { v1 = v0; b1 = b0; v0 = v; b0 = e; }
            else if (v > v1) { v1 = v;  b1 = e; }
        }
        float ex = expf(v1 - v0);
        e0a[t] = b0; e1a[t] = b1;
        w0a[t] = 1.f / (1.f + ex); w1a[t] = ex / (1.f + ex);
    }
}

// ---------------- per-block expert histogram (LDS atomics only) ----------------
__global__ __launch_bounds__(256) void k_count(const int* __restrict__ e0a,
        const int* __restrict__ e1a, int* __restrict__ block_cnt) {
    __shared__ int h[NEXP];
    if (threadIdx.x < NEXP) h[threadIdx.x] = 0;
    __syncthreads();
    int t = blockIdx.x * 256 + threadIdx.x;
    atomicAdd(&h[e0a[t]], 1);
    atomicAdd(&h[e1a[t]], 1);
    __syncthreads();
    if (threadIdx.x < NEXP)
        block_cnt[blockIdx.x * NEXP + threadIdx.x] = h[threadIdx.x];
}

// ---------------- serial scan: expert offsets + per-block bases ----------------
__global__ void k_offsets(const int* __restrict__ block_cnt, int* __restrict__ offs,
                          int* __restrict__ block_base) {
    int tot[NEXP];
    for (int e = 0; e < NEXP; e++) tot[e] = 0;
    for (int b = 0; b < CNT_BLOCKS; b++)
        for (int e = 0; e < NEXP; e++) tot[e] += block_cnt[b * NEXP + e];
    int s = 0, cur[NEXP];
    for (int e = 0; e < NEXP; e++) { offs[e] = s; cur[e] = s; s += tot[e]; }
    offs[NEXP] = s;
    for (int b = 0; b < CNT_BLOCKS; b++)
        for (int e = 0; e < NEXP; e++) {
            block_base[b * NEXP + e] = cur[e];
            cur[e] += block_cnt[b * NEXP + e];
        }
}

// ---------------- scatter with block-local LDS cursors (no global atomics) ----------------
__global__ __launch_bounds__(256) void k_scatter(const int* __restrict__ e0a,
        const int* __restrict__ e1a, const float* __restrict__ w0a,
        const float* __restrict__ w1a, const int* __restrict__ block_base,
        int* __restrict__ slot_tok, float* __restrict__ slot_w) {
    __shared__ int cur[NEXP];
    if (threadIdx.x < NEXP)
        cur[threadIdx.x] = block_base[blockIdx.x * NEXP + threadIdx.x];
    __syncthreads();
    int t = blockIdx.x * 256 + threadIdx.x;
    int p0 = atomicAdd(&cur[e0a[t]], 1);
    slot_tok[p0] = t; slot_w[p0] = w0a[t];
    int p1 = atomicAdd(&cur[e1a[t]], 1);
    slot_tok[p1] = t; slot_w[p1] = w1a[t];
}

// ---------------- transpose + cast: src[z][R][C] f32 -> dst[z][C][R] bf16 ----------------
__global__ __launch_bounds__(256) void k_transpose_cast(const float* __restrict__ src,
        unsigned short* __restrict__ dst, int R, int C) {
    __shared__ float tile[32][33];
    int z = blockIdx.z;
    const float* s = src + (size_t)z * R * C;
    unsigned short* d = dst + (size_t)z * R * C;
    int c0 = blockIdx.x * 32, r0 = blockIdx.y * 32;
    int tx = threadIdx.x & 31, ty = threadIdx.x >> 5;   // ty: 0..7
#pragma unroll
    for (int i = 0; i < 4; i++)
        tile[ty + i * 8][tx] = s[(size_t)(r0 + ty + i * 8) * C + c0 + tx];
    __syncthreads();
#pragma unroll
    for (int i = 0; i < 4; i++)
        d[(size_t)(c0 + ty + i * 8) * R + r0 + tx] = f2bf(tile[tx][ty + i * 8]);
}

// ---------------- grouped GEMM (m97 structure: 128x128 tile, BK=64, 4 waves) ----------------
// MODE 0: Hout[slot][colg] = bf16(gelu(acc + b1))      (A rows gathered if GATHER)
// MODE 1: atomicAdd(Out[tok][colg], w * (acc + b2))
template<int MODE, bool GATHER>
__global__ __launch_bounds__(256) void k_gemm(
    const unsigned short* __restrict__ A, int Astride,
    const unsigned short* __restrict__ Bt, size_t BtEStride, int BtRowStride,
    const float* __restrict__ bias, int biasEStride,
    const int* __restrict__ offs,
    const int* __restrict__ slot_tok, const float* __restrict__ slot_w,
    unsigned short* __restrict__ Hout, int HoutStride,
    float* __restrict__ Out,
    int K, int N)
{
    int e   = blockIdx.z;
    int off = offs ? offs[e] : 0;
    int cnt = offs ? (offs[e + 1] - off) : B_TOK;
    int m0  = blockIdx.x * 128;
    if (m0 >= cnt) return;
    int n0  = blockIdx.y * 128;
    const unsigned short* Bte = Bt + (size_t)e * BtEStride;

    __shared__ unsigned short Al[128 * 64];
    __shared__ unsigned short Bl[128 * 64];

    int tid = threadIdx.x;
    int w = tid >> 6, l = tid & 63;
    int larow = l >> 3;        // row within 8-row chunk
    int lk    = (l & 7) * 8;   // k element offset (16B granule)

    // per-thread source rows for the 4 staging chunks (fixed across K-steps)
    size_t asrc[4], bsrc[4];
#pragma unroll
    for (int i = 0; i < 4; i++) {
        int c = i * 4 + w;
        int r = c * 8 + larow;            // 0..127 within tile
        int gs = m0 + r;
        int srcrow;
        if (GATHER) {
            int slot = off + gs; if (slot > NSLOT - 1) slot = NSLOT - 1;
            srcrow = slot_tok[slot];
        } else {
            int slot = off + gs;
            int maxr = offs ? (NSLOT - 1) : (B_TOK - 1);
            if (slot > maxr) slot = maxr;
            srcrow = slot;
        }
        asrc[i] = (size_t)srcrow * Astride + lk;
        bsrc[i] = (size_t)(n0 + r) * BtRowStride + lk;
    }

    f32x4 acc[4][4];
#pragma unroll
    for (int mi = 0; mi < 4; mi++)
#pragma unroll
        for (int ni = 0; ni < 4; ni++) acc[mi][ni] = (f32x4){0.f, 0.f, 0.f, 0.f};

    int wr = w >> 1, wc = w & 1;
    int arow_f = wr * 64 + (l & 15);
    int brow_f = wc * 64 + (l & 15);
    int g = l >> 4;

    for (int k0 = 0; k0 < K; k0 += 64) {
#pragma unroll
        for (int i = 0; i < 4; i++) {
            int c = i * 4 + w;
            gl_lds16(A + asrc[i] + k0,   Al + (size_t)c * 512);
            gl_lds16(Bte + bsrc[i] + k0, Bl + (size_t)c * 512);
        }
        __syncthreads();
#pragma unroll
        for (int ks = 0; ks < 2; ks++) {
            bf16x8 af[4], bfr[4];
#pragma unroll
            for (int mi = 0; mi < 4; mi++)
                af[mi] = *(const bf16x8*)(Al + (size_t)(arow_f + mi * 16) * 64 + ks * 32 + g * 8);
#pragma unroll
            for (int ni = 0; ni < 4; ni++)
                bfr[ni] = *(const bf16x8*)(Bl + (size_t)(brow_f + ni * 16) * 64 + ks * 32 + g * 8);
#pragma unroll
            for (int mi = 0; mi < 4; mi++)
#pragma unroll
                for (int ni = 0; ni < 4; ni++)
                    acc[mi][ni] = __builtin_amdgcn_mfma_f32_16x16x32_bf16(
                        af[mi], bfr[ni], acc[mi][ni], 0, 0, 0);
        }
        __syncthreads();
    }

    // epilogue — C/D layout (verified): col = lane&15, row = (lane>>4)*4 + reg
    int rg = l >> 4, cl = l & 15;
    float bvs[4];
#pragma unroll
    for (int ni = 0; ni < 4; ni++) {
        int colg = n0 + wc * 64 + ni * 16 + cl;
        bvs[ni] = bias ? bias[(size_t)e * biasEStride + colg] : 0.f;
    }
#pragma unroll
    for (int mi = 0; mi < 4; mi++) {
#pragma unroll
        for (int j = 0; j < 4; j++) {
            int rl = wr * 64 + mi * 16 + rg * 4 + j;
            if (m0 + rl >= cnt) continue;
            int slot = off + m0 + rl;
            if (MODE == 0) {
#pragma unroll
                for (int ni = 0; ni < 4; ni++) {
                    int colg = n0 + wc * 64 + ni * 16 + cl;
                    float hv = acc[mi][ni][j] + bvs[ni];
                    float ge = 0.5f * hv * (1.f + erff(hv * 0.70710678118654752f));
                    Hout[(size_t)slot * HoutStride + colg] = f2bf(ge);
                }
            } else {
                int tok; float wgt;
                if (slot_w) { tok = slot_tok[slot]; wgt = slot_w[slot]; }
                else        { tok = slot;           wgt = 1.f; }
#pragma unroll
                for (int ni = 0; ni < 4; ni++) {
                    int colg = n0 + wc * 64 + ni * 16 + cl;
                    atomicAdd(&Out[(size_t)tok * DIM + colg], wgt * (acc[mi][ni][j] + bvs[ni]));
                }
            }
        }
    }
}

// ---------------- LayerNorm(acc + x) in-place on out ----------------
__global__ __launch_bounds__(256) void k_ln(float* __restrict__ out,
        const float* __restrict__ x, const float* __restrict__ gamma,
        const float* __restrict__ beta) {
    int wv = threadIdx.x >> 6, l = threadIdx.x & 63;
    int t = blockIdx.x * 4 + wv;
    float* orow = out + (size_t)t * DIM;
    const float* xrow = x + (size_t)t * DIM;
    float z[16];
    float s = 0.f;
#pragma unroll
    for (int it = 0; it < 4; it++) {
        int k0 = it * 256 + l * 4;
        float4 a = *(const float4*)(orow + k0);
        float4 b = *(const float4*)(xrow + k0);
        z[it * 4 + 0] = a.x + b.x; z[it * 4 + 1] = a.y + b.y;
        z[it * 4 + 2] = a.z + b.z; z[it * 4 + 3] = a.w + b.w;
        s += z[it * 4 + 0] + z[it * 4 + 1] + z[it * 4 + 2] + z[it * 4 + 3];
    }
#pragma unroll
    for (int off = 32; off; off >>= 1) s += __shfl_xor(s, off);
    float mu = s * (1.f / 1024.f);
    float vs = 0.f;
#pragma unroll
    for (int i = 0; i < 16; i++) { float d = z[i] - mu; vs += d * d; }
#pragma unroll
    for (int off = 32; off; off >>= 1) vs += __shfl_xor(vs, off);
    float rs = 1.f / sqrtf(vs * (1.f / 1024.f) + 1e-5f);
#pragma unroll
    for (int it = 0; it < 4; it++) {
        int k0 = it * 256 + l * 4;
        float4 gm = *(const float4*)(gamma + k0);
        float4 be = *(const float4*)(beta + k0);
        float4 o;
        o.x = (z[it * 4 + 0] - mu) * rs * gm.x + be.x;
        o.y = (z[it * 4 + 1] - mu) * rs * gm.y + be.y;
        o.z = (z[it * 4 + 2] - mu) * rs * gm.z + be.z;
        o.w = (z[it * 4 + 3] - mu) * rs * gm.w + be.w;
        *(float4*)(orow + k0) = o;
    }
}

// ---------------- launch ----------------
extern "C" void kernel_launch(void* const* d_in, const int* in_sizes, int n_in,
                              void* d_out, int out_size, void* d_ws, size_t ws_size,
                              hipStream_t stream) {
    (void)in_sizes; (void)n_in; (void)ws_size;
    const float* x      = (const float*)d_in[0];
    const float* gate_w = (const float*)d_in[1];
    const float* W1     = (const float*)d_in[2];
    const float* b1     = (const float*)d_in[3];
    const float* W2     = (const float*)d_in[4];
    const float* b2     = (const float*)d_in[5];
    const float* sW1    = (const float*)d_in[6];
    const float* sb1    = (const float*)d_in[7];
    const float* sW2    = (const float*)d_in[8];
    const float* sb2    = (const float*)d_in[9];
    const float* gamma  = (const float*)d_in[10];
    const float* beta   = (const float*)d_in[11];
    float* out = (float*)d_out;

    // workspace carve (total ~177 MB)
    char* p = (char*)d_ws;
    auto carve = [&](size_t n) { char* r = p; p += (n + 255) & ~(size_t)255; return r; };
    unsigned short* xb    = (unsigned short*)carve((size_t)B_TOK * DIM * 2);
    unsigned short* W1t   = (unsigned short*)carve((size_t)NEXP * FFN * DIM * 2); // [e][f][d]
    unsigned short* W2t   = (unsigned short*)carve((size_t)NEXP * DIM * FFN * 2); // [e][d][f]
    unsigned short* sW1t  = (unsigned short*)carve((size_t)FFN * DIM * 2);        // [f][d]
    unsigned short* sW2t  = (unsigned short*)carve((size_t)DIM * FFN * 2);        // [d][f]
    unsigned short* hbuf  = (unsigned short*)carve((size_t)NSLOT * FCHUNK * 2);   // 67 MB
    int*   e0a       = (int*)carve((size_t)B_TOK * 4);
    int*   e1a       = (int*)carve((size_t)B_TOK * 4);
    float* w0a       = (float*)carve((size_t)B_TOK * 4);
    float* w1a       = (float*)carve((size_t)B_TOK * 4);
    int*   slot_tok  = (int*)carve((size_t)NSLOT * 4);
    float* slot_w    = (float*)carve((size_t)NSLOT * 4);
    int*   block_cnt = (int*)carve((size_t)CNT_BLOCKS * NEXP * 4);
    int*   block_base= (int*)carve((size_t)CNT_BLOCKS * NEXP * 4);
    int*   offs      = (int*)carve(64);

    hipMemsetAsync(d_out, 0, (size_t)out_size * 4, stream);

    k_gate<<<B_TOK / 4, 256, 0, stream>>>(x, gate_w, xb, e0a, e1a, w0a, w1a);
    k_count<<<CNT_BLOCKS, 256, 0, stream>>>(e0a, e1a, block_cnt);
    k_offsets<<<1, 1, 0, stream>>>(block_cnt, offs, block_base);
    k_scatter<<<CNT_BLOCKS, 256, 0, stream>>>(e0a, e1a, w0a, w1a, block_base, slot_tok, slot_w);

    k_transpose_cast<<<dim3(FFN / 32, DIM / 32, NEXP), 256, 0, stream>>>(W1, W1t, DIM, FFN);
    k_transpose_cast<<<dim3(DIM / 32, FFN / 32, NEXP), 256, 0, stream>>>(W2, W2t, FFN, DIM);
    k_transpose_cast<<<dim3(FFN / 32, DIM / 32, 1), 256, 0, stream>>>(sW1, sW1t, DIM, FFN);
    k_transpose_cast<<<dim3(DIM / 32, FFN / 32, 1), 256, 0, stream>>>(sW2, sW2t, FFN, DIM);

    // experts: two FFN chunks of 1024, h staged in hbuf between the two GEMMs
    for (int c = 0; c < 2; c++) {
        size_t f0 = (size_t)c * FCHUNK;
        k_gemm<0, true><<<dim3(128, 8, NEXP), 256, 0, stream>>>(
            xb, DIM,
            W1t + f0 * DIM, (size_t)FFN * DIM, DIM,
            b1 + f0, FFN,
            offs, slot_tok, nullptr,
            hbuf, FCHUNK, nullptr, DIM, FCHUNK);
        k_gemm<1, false><<<dim3(128, 8, NEXP), 256, 0, stream>>>(
            hbuf, FCHUNK,
            W2t + f0, (size_t)DIM * FFN, FFN,
            (c == 0) ? b2 : nullptr, DIM,
            offs, slot_tok, slot_w,
            nullptr, 0, out, FCHUNK, DIM);
    }
    // shared expert: same machinery, identity routing, weight 1
    for (int c = 0; c < 2; c++) {
        size_t f0 = (size_t)c * FCHUNK;
        k_gemm<0, false><<<dim3(128, 8, 1), 256, 0, stream>>>(
            xb, DIM,
            sW1t + f0 * DIM, 0, DIM,
            sb1 + f0, 0,
            nullptr, nullptr, nullptr,
            hbuf, FCHUNK, nullptr, DIM, FCHUNK);
        k_gemm<1, false><<<dim3(128, 8, 1), 256, 0, stream>>>(
            hbuf, FCHUNK,
            sW2t + f0, 0, FFN,
            (c == 0) ? sb2 : nullptr, 0,
            nullptr, nullptr, nullptr,
            nullptr, 0, out, FCHUNK, DIM);
    }

    k_ln<<<B_TOK / 4, 256, 0, stream>>>(out, x, gamma, beta);
}

// Round 4
// 1111.891 us; speedup vs baseline: 1.6991x; 1.3185x over previous
//
#include <hip/hip_runtime.h>
#include <hip/hip_bf16.h>
#include <math.h>

// ---------------- constants ----------------
constexpr int B_TOK = 16384;
constexpr int DIM   = 1024;
constexpr int NEXP  = 8;
constexpr int FFN   = 2048;
constexpr int NSLOT = B_TOK * 2;     // top-2 -> exactly 2 slots per token
constexpr int FCHUNK = 1024;         // FFN processed in two 1024-wide chunks
constexpr int CNT_BLOCKS = B_TOK / 256;  // 64 blocks for count/scatter

typedef __attribute__((ext_vector_type(8))) short bf16x8;
typedef __attribute__((ext_vector_type(4))) float f32x4;

// fp32 -> bf16 round-to-nearest-even (values are finite/normal here)
static __device__ __forceinline__ unsigned short f2bf(float f) {
    unsigned int u = __float_as_uint(f);
    u += 0x7fffu + ((u >> 16) & 1u);
    return (unsigned short)(u >> 16);
}
static __device__ __forceinline__ float bf2f(unsigned short u) {
    return __uint_as_float(((unsigned int)u) << 16);
}

static __device__ __forceinline__ void gl_lds16(const unsigned short* g, unsigned short* s) {
    // async global->LDS, 16B per lane; LDS dest = wave-uniform base + lane*16
    __builtin_amdgcn_global_load_lds(
        (const __attribute__((address_space(1))) unsigned int*)g,
        (__attribute__((address_space(3))) unsigned int*)s, 16, 0, 0);
}

// ---------------- gating: logits + top-2 + softmax + x->bf16 (no LDS, no atomics) ----------------
__global__ __launch_bounds__(256) void k_gate(const float* __restrict__ x,
        const float* __restrict__ gw, unsigned short* __restrict__ xb,
        int* __restrict__ e0a, int* __restrict__ e1a,
        float* __restrict__ w0a, float* __restrict__ w1a) {
    int tid = threadIdx.x;
    int wv = tid >> 6, l = tid & 63;
    int t = blockIdx.x * 4 + wv;
    const float* xr = x + (size_t)t * DIM;
    unsigned short* xbr = xb + (size_t)t * DIM;
    const float4* gwv = (const float4*)gw;   // gw[k][e], float4 idx = k*2, k*2+1

    float acc[NEXP];
#pragma unroll
    for (int e = 0; e < NEXP; e++) acc[e] = 0.f;

#pragma unroll
    for (int it = 0; it < 4; it++) {
        int k0 = it * 256 + l * 4;
        float4 xv = *(const float4*)(xr + k0);
        *(ushort4*)(xbr + k0) = make_ushort4(f2bf(xv.x), f2bf(xv.y), f2bf(xv.z), f2bf(xv.w));
        float xs[4] = {xv.x, xv.y, xv.z, xv.w};
#pragma unroll
        for (int j = 0; j < 4; j++) {
            int k = k0 + j;
            float4 g0 = gwv[k * 2];
            float4 g1 = gwv[k * 2 + 1];
            float xs1 = xs[j];
            acc[0] += xs1 * g0.x; acc[1] += xs1 * g0.y;
            acc[2] += xs1 * g0.z; acc[3] += xs1 * g0.w;
            acc[4] += xs1 * g1.x; acc[5] += xs1 * g1.y;
            acc[6] += xs1 * g1.z; acc[7] += xs1 * g1.w;
        }
    }
#pragma unroll
    for (int e = 0; e < NEXP; e++) {
        float v = acc[e];
#pragma unroll
        for (int off = 32; off; off >>= 1) v += __shfl_xor(v, off);
        acc[e] = v;
    }
    if (l == 0) {
        int b0 = -1, b1 = -1;
        float v0 = -INFINITY, v1 = -INFINITY;
#pragma unroll
        for (int e = 0; e < NEXP; e++) {
            float v = acc[e];
            if (v > v0)      { v1 = v0; b1 = b0; v0 = v; b0 = e; }
            else if (v > v1) { v1 = v;  b1 = e; }
        }
        float ex = expf(v1 - v0);
        e0a[t] = b0; e1a[t] = b1;
        w0a[t] = 1.f / (1.f + ex); w1a[t] = ex / (1.f + ex);
    }
}

// ---------------- per-block expert histogram (LDS atomics only) ----------------
__global__ __launch_bounds__(256) void k_count(const int* __restrict__ e0a,
        const int* __restrict__ e1a, int* __restrict__ block_cnt) {
    __shared__ int h[NEXP];
    if (threadIdx.x < NEXP) h[threadIdx.x] = 0;
    __syncthreads();
    int t = blockIdx.x * 256 + threadIdx.x;
    atomicAdd(&h[e0a[t]], 1);
    atomicAdd(&h[e1a[t]], 1);
    __syncthreads();
    if (threadIdx.x < NEXP)
        block_cnt[blockIdx.x * NEXP + threadIdx.x] = h[threadIdx.x];
}

// ---------------- serial scan: expert offsets + per-block bases ----------------
__global__ void k_offsets(const int* __restrict__ block_cnt, int* __restrict__ offs,
                          int* __restrict__ block_base) {
    int tot[NEXP];
    for (int e = 0; e < NEXP; e++) tot[e] = 0;
    for (int b = 0; b < CNT_BLOCKS; b++)
        for (int e = 0; e < NEXP; e++) tot[e] += block_cnt[b * NEXP + e];
    int s = 0, cur[NEXP];
    for (int e = 0; e < NEXP; e++) { offs[e] = s; cur[e] = s; s += tot[e]; }
    offs[NEXP] = s;
    for (int b = 0; b < CNT_BLOCKS; b++)
        for (int e = 0; e < NEXP; e++) {
            block_base[b * NEXP + e] = cur[e];
            cur[e] += block_cnt[b * NEXP + e];
        }
}

// ---------------- scatter with block-local LDS cursors; records inverse map ----------------
__global__ __launch_bounds__(256) void k_scatter(const int* __restrict__ e0a,
        const int* __restrict__ e1a, const int* __restrict__ block_base,
        int* __restrict__ slot_tok, int* __restrict__ inv0, int* __restrict__ inv1) {
    __shared__ int cur[NEXP];
    if (threadIdx.x < NEXP)
        cur[threadIdx.x] = block_base[blockIdx.x * NEXP + threadIdx.x];
    __syncthreads();
    int t = blockIdx.x * 256 + threadIdx.x;
    int p0 = atomicAdd(&cur[e0a[t]], 1);
    slot_tok[p0] = t; inv0[t] = p0;
    int p1 = atomicAdd(&cur[e1a[t]], 1);
    slot_tok[p1] = t; inv1[t] = p1;
}

// ---------------- transpose + cast: src[z][R][C] f32 -> dst[z][C][R] bf16 ----------------
__global__ __launch_bounds__(256) void k_transpose_cast(const float* __restrict__ src,
        unsigned short* __restrict__ dst, int R, int C) {
    __shared__ float tile[32][33];
    int z = blockIdx.z;
    const float* s = src + (size_t)z * R * C;
    unsigned short* d = dst + (size_t)z * R * C;
    int c0 = blockIdx.x * 32, r0 = blockIdx.y * 32;
    int tx = threadIdx.x & 31, ty = threadIdx.x >> 5;   // ty: 0..7
#pragma unroll
    for (int i = 0; i < 4; i++)
        tile[ty + i * 8][tx] = s[(size_t)(r0 + ty + i * 8) * C + c0 + tx];
    __syncthreads();
#pragma unroll
    for (int i = 0; i < 4; i++)
        d[(size_t)(c0 + ty + i * 8) * R + r0 + tx] = f2bf(tile[tx][ty + i * 8]);
}

// ---------------- grouped GEMM (128x128 tile, BK=64, 4 waves, swizzled LDS) ----------------
// Output: O[slot][colg] = (GELU? gelu : id)(acc + bias)  [+= existing if RMW]
// O is bf16 (F32OUT=false) or fp32 (F32OUT=true). One writer per element, no atomics.
template<bool GELU, bool GATHER, bool RMW, bool F32OUT>
__global__ __launch_bounds__(256) void k_gemm(
    const unsigned short* __restrict__ A, int Astride,
    const unsigned short* __restrict__ Bt, size_t BtEStride, int BtRowStride,
    const float* __restrict__ bias, int biasEStride,
    const int* __restrict__ offs, const int* __restrict__ slot_tok,
    void* __restrict__ OutV, int OutStride, int K)
{
    int e   = blockIdx.z;
    int off = offs ? offs[e] : 0;
    int cnt = offs ? (offs[e + 1] - off) : B_TOK;
    int m0  = blockIdx.x * 128;
    if (m0 >= cnt) return;
    int n0  = blockIdx.y * 128;
    const unsigned short* Bte = Bt + (size_t)e * BtEStride;

    __shared__ unsigned short Al[128 * 64];
    __shared__ unsigned short Bl[128 * 64];

    int tid = threadIdx.x;
    int w = tid >> 6, l = tid & 63;
    int larow = l >> 3;        // row within 8-row chunk
    // pre-swizzled global k-granule: LDS stays linear, source granule = (l&7) ^ (row&7)
    int gsw = (((l & 7) ^ ((l >> 3) & 7)) * 8);

    // per-thread source rows for the 4 staging chunks (fixed across K-steps)
    size_t asrc[4], bsrc[4];
#pragma unroll
    for (int i = 0; i < 4; i++) {
        int c = i * 4 + w;
        int r = c * 8 + larow;            // 0..127 within tile
        int gs = m0 + r;
        int srcrow;
        if (GATHER) {
            int slot = off + gs; if (slot > NSLOT - 1) slot = NSLOT - 1;
            srcrow = slot_tok[slot];
        } else {
            int slot = off + gs;
            int maxr = offs ? (NSLOT - 1) : (B_TOK - 1);
            if (slot > maxr) slot = maxr;
            srcrow = slot;
        }
        asrc[i] = (size_t)srcrow * Astride + gsw;
        bsrc[i] = (size_t)(n0 + r) * BtRowStride + gsw;
    }

    f32x4 acc[4][4];
#pragma unroll
    for (int mi = 0; mi < 4; mi++)
#pragma unroll
        for (int ni = 0; ni < 4; ni++) acc[mi][ni] = (f32x4){0.f, 0.f, 0.f, 0.f};

    int wr = w >> 1, wc = w & 1;
    int arow_f = wr * 64 + (l & 15);   // (arow_f & 7) == (l & 7)
    int brow_f = wc * 64 + (l & 15);
    int g = l >> 4;
    int r7 = l & 7;

    for (int k0 = 0; k0 < K; k0 += 64) {
#pragma unroll
        for (int i = 0; i < 4; i++) {
            int c = i * 4 + w;
            gl_lds16(A + asrc[i] + k0,   Al + (size_t)c * 512);
            gl_lds16(Bte + bsrc[i] + k0, Bl + (size_t)c * 512);
        }
        __syncthreads();
#pragma unroll
        for (int ks = 0; ks < 2; ks++) {
            int kg = ((ks * 4 + g) ^ r7) * 8;   // swizzled granule offset (elems)
            bf16x8 af[4], bfr[4];
#pragma unroll
            for (int mi = 0; mi < 4; mi++)
                af[mi] = *(const bf16x8*)(Al + (size_t)(arow_f + mi * 16) * 64 + kg);
#pragma unroll
            for (int ni = 0; ni < 4; ni++)
                bfr[ni] = *(const bf16x8*)(Bl + (size_t)(brow_f + ni * 16) * 64 + kg);
#pragma unroll
            for (int mi = 0; mi < 4; mi++)
#pragma unroll
                for (int ni = 0; ni < 4; ni++)
                    acc[mi][ni] = __builtin_amdgcn_mfma_f32_16x16x32_bf16(
                        af[mi], bfr[ni], acc[mi][ni], 0, 0, 0);
        }
        __syncthreads();
    }

    // epilogue — C/D layout (verified): col = lane&15, row = (lane>>4)*4 + reg
    int rg = l >> 4, cl = l & 15;
    float bvs[4];
#pragma unroll
    for (int ni = 0; ni < 4; ni++) {
        int colg = n0 + wc * 64 + ni * 16 + cl;
        bvs[ni] = bias ? bias[(size_t)e * biasEStride + colg] : 0.f;
    }
#pragma unroll
    for (int mi = 0; mi < 4; mi++) {
#pragma unroll
        for (int j = 0; j < 4; j++) {
            int rl = wr * 64 + mi * 16 + rg * 4 + j;
            if (m0 + rl >= cnt) continue;
            int slot = off + m0 + rl;
#pragma unroll
            for (int ni = 0; ni < 4; ni++) {
                int colg = n0 + wc * 64 + ni * 16 + cl;
                float hv = acc[mi][ni][j] + bvs[ni];
                if (GELU) hv = 0.5f * hv * (1.f + erff(hv * 0.70710678118654752f));
                size_t idx = (size_t)slot * OutStride + colg;
                if (F32OUT) {
                    float* O = (float*)OutV;
                    if (RMW) hv += O[idx];
                    O[idx] = hv;
                } else {
                    unsigned short* O = (unsigned short*)OutV;
                    if (RMW) hv += bf2f(O[idx]);
                    O[idx] = f2bf(hv);
                }
            }
        }
    }
}

// ---------------- fused combine + LayerNorm ----------------
// out[t] = LN( x[t] + w0*yb[inv0[t]] + w1*yb[inv1[t]] + shared[t] ), shared lives in out (fp32)
__global__ __launch_bounds__(256) void k_combine_ln(
        const float* __restrict__ x, const unsigned short* __restrict__ yb,
        const int* __restrict__ inv0, const int* __restrict__ inv1,
        const float* __restrict__ w0a, const float* __restrict__ w1a,
        const float* __restrict__ gamma, const float* __restrict__ beta,
        float* __restrict__ out) {
    int wv = threadIdx.x >> 6, l = threadIdx.x & 63;
    int t = blockIdx.x * 4 + wv;
    int s0 = inv0[t], s1 = inv1[t];
    float w0 = w0a[t], w1 = w1a[t];
    const float* xr = x + (size_t)t * DIM;
    const unsigned short* y0r = yb + (size_t)s0 * DIM;
    const unsigned short* y1r = yb + (size_t)s1 * DIM;
    float* orow = out + (size_t)t * DIM;

    float z[16];
    float s = 0.f;
#pragma unroll
    for (int it = 0; it < 4; it++) {
        int k0 = it * 256 + l * 4;
        float4 xv = *(const float4*)(xr + k0);
        float4 sh = *(const float4*)(orow + k0);
        ushort4 a = *(const ushort4*)(y0r + k0);
        ushort4 b = *(const ushort4*)(y1r + k0);
        z[it * 4 + 0] = xv.x + sh.x + w0 * bf2f(a.x) + w1 * bf2f(b.x);
        z[it * 4 + 1] = xv.y + sh.y + w0 * bf2f(a.y) + w1 * bf2f(b.y);
        z[it * 4 + 2] = xv.z + sh.z + w0 * bf2f(a.z) + w1 * bf2f(b.z);
        z[it * 4 + 3] = xv.w + sh.w + w0 * bf2f(a.w) + w1 * bf2f(b.w);
        s += z[it * 4 + 0] + z[it * 4 + 1] + z[it * 4 + 2] + z[it * 4 + 3];
    }
#pragma unroll
    for (int off = 32; off; off >>= 1) s += __shfl_xor(s, off);
    float mu = s * (1.f / 1024.f);
    float vs = 0.f;
#pragma unroll
    for (int i = 0; i < 16; i++) { float d = z[i] - mu; vs += d * d; }
#pragma unroll
    for (int off = 32; off; off >>= 1) vs += __shfl_xor(vs, off);
    float rs = 1.f / sqrtf(vs * (1.f / 1024.f) + 1e-5f);
#pragma unroll
    for (int it = 0; it < 4; it++) {
        int k0 = it * 256 + l * 4;
        float4 gm = *(const float4*)(gamma + k0);
        float4 be = *(const float4*)(beta + k0);
        float4 o;
        o.x = (z[it * 4 + 0] - mu) * rs * gm.x + be.x;
        o.y = (z[it * 4 + 1] - mu) * rs * gm.y + be.y;
        o.z = (z[it * 4 + 2] - mu) * rs * gm.z + be.z;
        o.w = (z[it * 4 + 3] - mu) * rs * gm.w + be.w;
        *(float4*)(orow + k0) = o;
    }
}

// ---------------- launch ----------------
extern "C" void kernel_launch(void* const* d_in, const int* in_sizes, int n_in,
                              void* d_out, int out_size, void* d_ws, size_t ws_size,
                              hipStream_t stream) {
    (void)in_sizes; (void)n_in; (void)ws_size; (void)out_size;
    const float* x      = (const float*)d_in[0];
    const float* gate_w = (const float*)d_in[1];
    const float* W1     = (const float*)d_in[2];
    const float* b1     = (const float*)d_in[3];
    const float* W2     = (const float*)d_in[4];
    const float* b2     = (const float*)d_in[5];
    const float* sW1    = (const float*)d_in[6];
    const float* sb1    = (const float*)d_in[7];
    const float* sW2    = (const float*)d_in[8];
    const float* sb2    = (const float*)d_in[9];
    const float* gamma  = (const float*)d_in[10];
    const float* beta   = (const float*)d_in[11];
    float* out = (float*)d_out;

    // workspace carve (total ~244 MB)
    char* p = (char*)d_ws;
    auto carve = [&](size_t n) { char* r = p; p += (n + 255) & ~(size_t)255; return r; };
    unsigned short* xb    = (unsigned short*)carve((size_t)B_TOK * DIM * 2);
    unsigned short* W1t   = (unsigned short*)carve((size_t)NEXP * FFN * DIM * 2); // [e][f][d]
    unsigned short* W2t   = (unsigned short*)carve((size_t)NEXP * DIM * FFN * 2); // [e][d][f]
    unsigned short* sW1t  = (unsigned short*)carve((size_t)FFN * DIM * 2);        // [f][d]
    unsigned short* sW2t  = (unsigned short*)carve((size_t)DIM * FFN * 2);        // [d][f]
    unsigned short* hbuf  = (unsigned short*)carve((size_t)NSLOT * FCHUNK * 2);   // 67 MB
    unsigned short* ybuf  = (unsigned short*)carve((size_t)NSLOT * DIM * 2);      // 67 MB
    int*   e0a       = (int*)carve((size_t)B_TOK * 4);
    int*   e1a       = (int*)carve((size_t)B_TOK * 4);
    float* w0a       = (float*)carve((size_t)B_TOK * 4);
    float* w1a       = (float*)carve((size_t)B_TOK * 4);
    int*   slot_tok  = (int*)carve((size_t)NSLOT * 4);
    int*   inv0      = (int*)carve((size_t)B_TOK * 4);
    int*   inv1      = (int*)carve((size_t)B_TOK * 4);
    int*   block_cnt = (int*)carve((size_t)CNT_BLOCKS * NEXP * 4);
    int*   block_base= (int*)carve((size_t)CNT_BLOCKS * NEXP * 4);
    int*   offs      = (int*)carve(64);

    k_gate<<<B_TOK / 4, 256, 0, stream>>>(x, gate_w, xb, e0a, e1a, w0a, w1a);
    k_count<<<CNT_BLOCKS, 256, 0, stream>>>(e0a, e1a, block_cnt);
    k_offsets<<<1, 1, 0, stream>>>(block_cnt, offs, block_base);
    k_scatter<<<CNT_BLOCKS, 256, 0, stream>>>(e0a, e1a, block_base, slot_tok, inv0, inv1);

    k_transpose_cast<<<dim3(FFN / 32, DIM / 32, NEXP), 256, 0, stream>>>(W1, W1t, DIM, FFN);
    k_transpose_cast<<<dim3(DIM / 32, FFN / 32, NEXP), 256, 0, stream>>>(W2, W2t, FFN, DIM);
    k_transpose_cast<<<dim3(FFN / 32, DIM / 32, 1), 256, 0, stream>>>(sW1, sW1t, DIM, FFN);
    k_transpose_cast<<<dim3(DIM / 32, FFN / 32, 1), 256, 0, stream>>>(sW2, sW2t, FFN, DIM);

    // experts: two FFN chunks; GEMM1 -> hbuf (gelu bf16), GEMM2 -> ybuf (bf16, RMW on c=1)
    // chunk 0
    k_gemm<true, true, false, false><<<dim3(128, 8, NEXP), 256, 0, stream>>>(
        xb, DIM, W1t, (size_t)FFN * DIM, DIM, b1, FFN,
        offs, slot_tok, hbuf, FCHUNK, DIM);
    k_gemm<false, false, false, false><<<dim3(128, 8, NEXP), 256, 0, stream>>>(
        hbuf, FCHUNK, W2t, (size_t)DIM * FFN, FFN, b2, DIM,
        offs, slot_tok, ybuf, DIM, FCHUNK);
    // chunk 1
    k_gemm<true, true, false, false><<<dim3(128, 8, NEXP), 256, 0, stream>>>(
        xb, DIM, W1t + (size_t)FCHUNK * DIM, (size_t)FFN * DIM, DIM, b1 + FCHUNK, FFN,
        offs, slot_tok, hbuf, FCHUNK, DIM);
    k_gemm<false, false, true, false><<<dim3(128, 8, NEXP), 256, 0, stream>>>(
        hbuf, FCHUNK, W2t + FCHUNK, (size_t)DIM * FFN, FFN, nullptr, 0,
        offs, slot_tok, ybuf, DIM, FCHUNK);

    // shared expert: GEMM1 -> hbuf, GEMM2 -> d_out (fp32, RMW on c=1)
    // chunk 0
    k_gemm<true, false, false, false><<<dim3(128, 8, 1), 256, 0, stream>>>(
        xb, DIM, sW1t, 0, DIM, sb1, 0,
        nullptr, nullptr, hbuf, FCHUNK, DIM);
    k_gemm<false, false, false, true><<<dim3(128, 8, 1), 256, 0, stream>>>(
        hbuf, FCHUNK, sW2t, 0, FFN, sb2, 0,
        nullptr, nullptr, out, DIM, FCHUNK);
    // chunk 1
    k_gemm<true, false, false, false><<<dim3(128, 8, 1), 256, 0, stream>>>(
        xb, DIM, sW1t + (size_t)FCHUNK * DIM, 0, DIM, sb1 + FCHUNK, 0,
        nullptr, nullptr, hbuf, FCHUNK, DIM);
    k_gemm<false, false, true, true><<<dim3(128, 8, 1), 256, 0, stream>>>(
        hbuf, FCHUNK, sW2t + FCHUNK, 0, FFN, nullptr, 0,
        nullptr, nullptr, out, DIM, FCHUNK);

    k_combine_ln<<<B_TOK / 4, 256, 0, stream>>>(x, ybuf, inv0, inv1, w0a, w1a,
                                                gamma, beta, out);
}